// Round 12
// baseline (340.217 us; speedup 1.0000x reference)
//
#include <hip/hip_runtime.h>

typedef unsigned short u16;
typedef __bf16 bf16x8 __attribute__((ext_vector_type(8)));
typedef float f32x4 __attribute__((ext_vector_type(4)));
typedef unsigned int u32x4 __attribute__((ext_vector_type(4)));
typedef u16 u16x4 __attribute__((ext_vector_type(4)));

#define LOG2E 1.44269504089f
#define SOFF 16.0f  // constant softmax offset (normalization is global, any constant works)

__device__ __forceinline__ f32x4 mfma16(bf16x8 a, bf16x8 b, f32x4 c) {
    return __builtin_amdgcn_mfma_f32_16x16x32_bf16(a, b, c, 0, 0, 0);
}
__device__ __forceinline__ u16 f2bf(float f) {  // RNE fp32 -> bf16
    union { float f; unsigned u; } x; x.f = f;
    unsigned r = x.u + 0x7FFFu + ((x.u >> 16) & 1u);
    return (u16)(r >> 16);
}
__device__ __forceinline__ float bf2f(u16 u) {
    union { unsigned u; float f; } x; x.u = ((unsigned)u) << 16;
    return x.f;
}
// async global->LDS, 16B per lane, wave-uniform LDS base + lane*16
__device__ __forceinline__ void gload_lds16(const u16* g, u16* l) {
    __builtin_amdgcn_global_load_lds((const __attribute__((address_space(1))) unsigned int*)g,
                                     (__attribute__((address_space(3))) unsigned int*)l, 16, 0, 0);
}

// ---------------- fused prep kernel ----------------
__device__ __forceinline__ void transp_tile(const float* __restrict__ in, u16* __restrict__ out,
                                            int R, int C, int r0, int c0,
                                            float (*t)[33], int tid) {
    const int tx = tid & 31, ty = tid >> 5;
#pragma unroll
    for (int k = 0; k < 4; ++k) t[ty + k * 8][tx] = in[(size_t)(r0 + ty + k * 8) * C + c0 + tx];
    __syncthreads();
#pragma unroll
    for (int k = 0; k < 4; ++k) out[(size_t)(c0 + ty + k * 8) * R + r0 + tx] = f2bf(t[tx][ty + k * 8]);
}

__global__ __launch_bounds__(256) void prep_kernel(
    const float* __restrict__ x,
    const float* __restrict__ wq, const float* __restrict__ wk,
    const float* __restrict__ wv, const float* __restrict__ wo,
    const float* __restrict__ w1, const float* __restrict__ w2,
    const float* __restrict__ mask, const int* __restrict__ protok,
    u16* __restrict__ hbf, u16* __restrict__ wqT, u16* __restrict__ wkT,
    u16* __restrict__ wvT, u16* __restrict__ woT, u16* __restrict__ w1T, u16* __restrict__ w2T,
    float* __restrict__ padneg, float* __restrict__ nzf) {
    __shared__ float t[32][33];
    __shared__ int red[256];
    const int id = blockIdx.x, tid = threadIdx.x;
    if (id < 1024) {
        const int z = id >> 8, rem = id & 255;
        const float* in = z == 0 ? wq : (z == 1 ? wk : (z == 2 ? wv : wo));
        u16* out = z == 0 ? wqT : (z == 1 ? wkT : (z == 2 ? wvT : woT));
        transp_tile(in, out, 512, 512, (rem >> 4) * 32, (rem & 15) * 32, t, tid);
    } else if (id < 2048) {
        const int rem = id - 1024;  // w1 [512,2048] -> w1T [2048,512]
        transp_tile(w1, w1T, 512, 2048, (rem >> 6) * 32, (rem & 63) * 32, t, tid);
    } else if (id < 3072) {
        const int rem = id - 2048;  // w2 [2048,512] -> w2T [512,2048]
        transp_tile(w2, w2T, 2048, 512, (rem >> 4) * 32, (rem & 15) * 32, t, tid);
    } else if (id < 4096) {
        const int i = ((id - 3072) * 256 + tid) * 8;
        f32x4 a = *(const f32x4*)(x + i);
        f32x4 b = *(const f32x4*)(x + i + 4);
        u16x4 o0, o1;
#pragma unroll
        for (int k = 0; k < 4; ++k) { o0[k] = f2bf(a[k]); o1[k] = f2bf(b[k]); }
        *(u16x4*)(hbf + i) = o0;
        *(u16x4*)(hbf + i + 4) = o1;
    } else if (id == 4096) {
        for (int i = tid; i < 4096; i += 256) {
            const int b = i >> 10, s = i & 1023;
            const float m = mask[(size_t)((b << 10) + s) * 1024 + s];
            padneg[i] = (m > 0.5f) ? -1.5e9f : -SOFF;
        }
    } else {
        int c = 0;
        for (int i = tid; i < 1024; i += 256) c += (protok[i] != 0) ? 1 : 0;
        red[tid] = c;
        __syncthreads();
        for (int s = 128; s > 0; s >>= 1) {
            if (tid < s) red[tid] += red[tid + s];
            __syncthreads();
        }
        if (tid == 0) nzf[0] = (float)red[0];
    }
}

// ---------------- GEMM: C[M,N] = A[M,K](bf16) * Bt[N,K]^T(bf16) ----------------
// BK=128 as two independently-swizzled 64-wide LDS halves: one barrier pair per 128 K.
// (r11 lesson: explicit dbuf does NOT help — vmcnt is a single in-order counter, the
// barrier drain waits for the prefetch too; 2-barrier structure is the local optimum.)
// XCD-aware block swizzle (same-m -> same XCD). Requires gridDim.y % 8 == 0, K % 128 == 0.
// MODE 0: fused QKV -> q:[B,H,S,D] bf16, k scaled LOG2E/8, v -> vT:[B,H,D,S] bf16 (N=1536)
// MODE 1: fp32 out + bias
// MODE 2: bf16 out + bias + relu
template <int BM, int BN, int MODE>
__global__ __launch_bounds__(256) void gemm_bf16(
    const u16* __restrict__ A,
    const u16* __restrict__ Bt0, const u16* __restrict__ Bt1, const u16* __restrict__ Bt2,
    const float* __restrict__ bias0, const float* __restrict__ bias1, const float* __restrict__ bias2,
    void* __restrict__ dst0, void* __restrict__ dst1, void* __restrict__ dst2,
    const int K, const int N) {
    constexpr int BK = 128;
    constexpr int WM = BM / 2, WN = BN / 2, MI = WM / 16, NI = WN / 16;
    __shared__ u16 lA[2 * BM * 64];   // [half][row][64]
    __shared__ u16 lB[2 * BN * 64];
    const int tid = threadIdx.x;
    const int w = tid >> 6, lane = tid & 63, q = lane >> 4, ln = lane & 15;
    const int wm = w >> 1, wn = w & 1;
    const int id = blockIdx.y * gridDim.x + blockIdx.x;
    const int mper = gridDim.y >> 3;
    const int rest = id >> 3;
    const int by = (id & 7) * mper + (rest % mper);
    const int bx = rest / mper;
    const int n0 = bx * BN, m0 = by * BM;
    const int rr = lane >> 3;                 // row within an 8-row staging group
    const int cs = ((lane & 7) ^ rr) * 8;     // swizzled k-offset within a half

    const u16* Bt;
    const float* bias;
    int nb, sel = 0;
    if (MODE == 0) {
        sel = n0 >> 9;
        Bt = sel == 0 ? Bt0 : (sel == 1 ? Bt1 : Bt2);
        bias = sel == 0 ? bias0 : (sel == 1 ? bias1 : bias2);
        nb = n0 & 511;
    } else {
        Bt = Bt0; bias = bias0; nb = n0;
    }

    const f32x4 vzero = {0.f, 0.f, 0.f, 0.f};
    f32x4 acc[MI][NI];
#pragma unroll
    for (int i = 0; i < MI; ++i)
#pragma unroll
        for (int j = 0; j < NI; ++j) acc[i][j] = vzero;

    const int swa = ln & 7;  // fragment-read swizzle key (row&7 == ln&7)
    for (int k0 = 0; k0 < K; k0 += BK) {
        const u16* Ag = A + (size_t)m0 * K + k0;
        const u16* Bg = Bt + (size_t)nb * K + k0;
#pragma unroll
        for (int hh = 0; hh < 2; ++hh) {
#pragma unroll
            for (int c = 0; c < BM / 32; ++c) {
                const int r = (w * (BM / 32) + c) * 8;
                gload_lds16(Ag + (size_t)(r + rr) * K + hh * 64 + cs, &lA[hh * BM * 64 + r * 64]);
            }
#pragma unroll
            for (int c = 0; c < BN / 32; ++c) {
                const int r = (w * (BN / 32) + c) * 8;
                gload_lds16(Bg + (size_t)(r + rr) * K + hh * 64 + cs, &lB[hh * BN * 64 + r * 64]);
            }
        }
        __syncthreads();
#pragma unroll
        for (int kb = 0; kb < 4; ++kb) {
            const u16* pA = &lA[(kb >> 1) * BM * 64];
            const u16* pB = &lB[(kb >> 1) * BN * 64];
            const int kk = kb & 1;
            bf16x8 af[MI], bfr[NI];
#pragma unroll
            for (int mi = 0; mi < MI; ++mi)
                af[mi] = *(const bf16x8*)&pA[(wm * WM + mi * 16 + ln) * 64 + ((((kk << 2) + q) ^ swa) << 3)];
#pragma unroll
            for (int ni = 0; ni < NI; ++ni)
                bfr[ni] = *(const bf16x8*)&pB[(wn * WN + ni * 16 + ln) * 64 + ((((kk << 2) + q) ^ swa) << 3)];
#pragma unroll
            for (int mi = 0; mi < MI; ++mi)
#pragma unroll
                for (int ni = 0; ni < NI; ++ni) acc[mi][ni] = mfma16(af[mi], bfr[ni], acc[mi][ni]);
        }
        __syncthreads();
    }

    const float scl = (MODE == 0 && sel == 1) ? 0.125f * LOG2E : 1.0f;
#pragma unroll
    for (int mi = 0; mi < MI; ++mi) {
#pragma unroll
        for (int ni = 0; ni < NI; ++ni) {
            const int col = n0 + wn * WN + ni * 16 + ln;
            const float bv = bias[MODE == 0 ? (col & 511) : col];
#pragma unroll
            for (int r = 0; r < 4; ++r) {
                const int row = m0 + wm * WM + mi * 16 + q * 4 + r;
                const float v = (acc[mi][ni][r] + bv) * scl;
                if (MODE == 0) {
                    const int cc = col & 511, hh = cc >> 6, dd = cc & 63;
                    const int bb = row >> 10, ss = row & 1023;
                    if (sel < 2) {
                        u16* dq = (u16*)(sel == 0 ? dst0 : dst1);
                        dq[(((bb << 3) + hh) * 1024 + ss) * 64 + dd] = f2bf(v);
                    } else {  // v written transposed: [B,H,D,S]
                        ((u16*)dst2)[(((bb << 3) + hh) * 64 + dd) * 1024 + ss] = f2bf(v);
                    }
                } else if (MODE == 1) {
                    ((float*)dst0)[(size_t)row * N + col] = v;
                } else {
                    ((u16*)dst0)[(size_t)row * N + col] = f2bf(fmaxf(v, 0.f));
                }
            }
        }
    }
}

// ---------------- WO GEMM with fused scale_o ----------------
// A[row, k=h*64+d] = (sum_c Ounc[c][bh][i][d]) * nz/Z[bh] synthesized in the staging phase.
// BK=128 (2 heads per K-tile). B (woT) keeps the DMA staging path. 64x64 tiles.
__global__ __launch_bounds__(256) void gemm_wo(
    const u16* __restrict__ Ounc, const float* __restrict__ blkZ, const float* __restrict__ nzf,
    const u16* __restrict__ Bt, const float* __restrict__ bias,
    float* __restrict__ dst) {
    constexpr int BM = 64, BN = 64, N = 512;
    constexpr int WM = 32, WN = 32, MI = 2, NI = 2;
    __shared__ u16 lA[2 * BM * 64];
    __shared__ u16 lB[2 * BN * 64];
    __shared__ float facsh[8];
    const int tid = threadIdx.x;
    const int w = tid >> 6, lane = tid & 63, q = lane >> 4, ln = lane & 15;
    const int wm = w >> 1, wn = w & 1;
    const int id = blockIdx.y * gridDim.x + blockIdx.x;  // grid 8 x 64
    const int mper = gridDim.y >> 3;
    const int rest = id >> 3;
    const int by = (id & 7) * mper + (rest % mper);
    const int bx = rest / mper;
    const int n0 = bx * BN, m0 = by * BM;
    const int b = m0 >> 10, mi0 = m0 & 1023;
    const int rr = lane >> 3;
    const int cs = ((lane & 7) ^ rr) * 8;

    // per-block: fac[h] = nz / Z[b,h], reduced from 16 blkZ partials (2 ck x 8 ig)
    {
        const int h = tid >> 5, sub = tid & 31;           // 8 h-groups of 32 threads
        float v = (sub < 16) ? blkZ[((sub >> 3) << 8) + ((b << 3) + h) * 8 + (sub & 7)] : 0.f;
#pragma unroll
        for (int o = 1; o < 32; o <<= 1) v += __shfl_xor(v, o);
        if (sub == 0) facsh[h] = nzf[0] / v;
    }
    __syncthreads();

    const f32x4 vzero = {0.f, 0.f, 0.f, 0.f};
    f32x4 acc[MI][NI];
#pragma unroll
    for (int i = 0; i < MI; ++i)
#pragma unroll
        for (int j = 0; j < NI; ++j) acc[i][j] = vzero;

    const int ra = tid >> 2;                 // A-synthesis: row (0..63)
    const int dseg = (tid & 3) * 16;         // 16 d per thread per head
    const int swa = ln & 7;
    for (int k0 = 0; k0 < 512; k0 += 128) {
        const int h0 = k0 >> 6;  // first head of this K-tile
        // ---- A synthesis: per half (head), sum 2 bf16 chunks, scale, swizzled ds_write ----
#pragma unroll
        for (int hh = 0; hh < 2; ++hh) {
            const int h = h0 + hh;
            const float fac = facsh[h];
            const size_t gi = (size_t)(((b << 3) + h) << 10) + mi0 + ra;
            float vals[16];
#pragma unroll
            for (int k = 0; k < 16; ++k) vals[k] = 0.f;
#pragma unroll
            for (int c = 0; c < 2; ++c) {
                const u16* src = Ounc + (((size_t)c) << 21) + gi * 64 + dseg;
                bf16x8 x0 = *(const bf16x8*)src;
                bf16x8 x1 = *(const bf16x8*)(src + 8);
#pragma unroll
                for (int k = 0; k < 8; ++k) { vals[k] += (float)x0[k]; vals[k + 8] += (float)x1[k]; }
            }
            u16 tmp[16];
#pragma unroll
            for (int k = 0; k < 16; ++k) tmp[k] = f2bf(vals[k] * fac);
            const int c0 = (tid & 3) * 2;
            u16* dstl = &lA[hh * BM * 64 + ra * 64];
            *(u32x4*)&dstl[(c0 ^ (ra & 7)) << 3] = *(u32x4*)&tmp[0];
            *(u32x4*)&dstl[((c0 + 1) ^ (ra & 7)) << 3] = *(u32x4*)&tmp[8];
        }
        // ---- B staging via DMA (two halves) ----
        const u16* Bg = Bt + (size_t)n0 * 512 + k0;
#pragma unroll
        for (int hh = 0; hh < 2; ++hh) {
#pragma unroll
            for (int c = 0; c < BN / 32; ++c) {
                const int r = (w * (BN / 32) + c) * 8;
                gload_lds16(Bg + (size_t)(r + rr) * 512 + hh * 64 + cs, &lB[hh * BN * 64 + r * 64]);
            }
        }
        __syncthreads();
#pragma unroll
        for (int kb = 0; kb < 4; ++kb) {
            const u16* pA = &lA[(kb >> 1) * BM * 64];
            const u16* pB = &lB[(kb >> 1) * BN * 64];
            const int kk = kb & 1;
            bf16x8 af[MI], bfr[NI];
#pragma unroll
            for (int mi = 0; mi < MI; ++mi)
                af[mi] = *(const bf16x8*)&pA[(wm * WM + mi * 16 + ln) * 64 + ((((kk << 2) + q) ^ swa) << 3)];
#pragma unroll
            for (int ni = 0; ni < NI; ++ni)
                bfr[ni] = *(const bf16x8*)&pB[(wn * WN + ni * 16 + ln) * 64 + ((((kk << 2) + q) ^ swa) << 3)];
#pragma unroll
            for (int mi = 0; mi < MI; ++mi)
#pragma unroll
                for (int ni = 0; ni < NI; ++ni) acc[mi][ni] = mfma16(af[mi], bfr[ni], acc[mi][ni]);
        }
        __syncthreads();
    }

#pragma unroll
    for (int mi = 0; mi < MI; ++mi) {
#pragma unroll
        for (int ni = 0; ni < NI; ++ni) {
            const int col = n0 + wn * WN + ni * 16 + ln;
            const float bv = bias[col];
#pragma unroll
            for (int r = 0; r < 4; ++r) {
                const int row = m0 + wm * WM + mi * 16 + q * 4 + r;
                dst[(size_t)row * N + col] = acc[mi][ni][r] + bv;
            }
        }
    }
}

// ---------------- flash attention: 2 i-tiles/block, 2 j-chunks, LDS-staged tiles ----------------
#define PSTR 68
__global__ __launch_bounds__(256) void flash_kernel(
    const u16* __restrict__ Kb, const u16* __restrict__ Qb, const u16* __restrict__ VT,
    const float* __restrict__ padneg,
    u16* __restrict__ Ounc, float* __restrict__ blkZ) {
    __shared__ u16 ldsQ[64 * 64];   // [j-local][d], row 128B, swizzled chunks
    __shared__ u16 ldsV[64 * 64];   // [d][j-local], row 128B, swizzled chunks
    __shared__ u16 P[4][16 * PSTR];
    __shared__ float zred[4];
    const int blk = blockIdx.x, ck = blockIdx.y;  // blk = bh*8+ig, ck in {0,1}
    const int ig = blk & 7, bh = blk >> 3, b = bh >> 3;
    const int i0 = ig << 7;
    const int tid = threadIdx.x;
    const int w = tid >> 6, lane = tid & 63, q = lane >> 4, ln = lane & 15;

    bf16x8 af[2][2];
    float pi[2][4];
    const float* pn = padneg + (b << 10);
#pragma unroll
    for (int it = 0; it < 2; ++it) {
        const u16* Ka = Kb + ((bh << 10) + i0 + (it << 6) + (w << 4) + ln) * 64;
        af[it][0] = *(const bf16x8*)(Ka + q * 8);
        af[it][1] = *(const bf16x8*)(Ka + 32 + q * 8);
#pragma unroll
        for (int r = 0; r < 4; ++r) pi[it][r] = pn[i0 + (it << 6) + (w << 4) + (q << 2) + r];
    }
    const u16* Qbase = Qb + (bh << 10) * 64;
    const u16* Vbase = VT + (bh << 6) * 1024;

    float lsum[2][4] = {{0.f, 0.f, 0.f, 0.f}, {0.f, 0.f, 0.f, 0.f}};
    const f32x4 vzero = {0.f, 0.f, 0.f, 0.f};
    f32x4 acc[2][4];
#pragma unroll
    for (int it = 0; it < 2; ++it)
#pragma unroll
        for (int ds = 0; ds < 4; ++ds) acc[it][ds] = vzero;
    u16* Pw = &P[w][0];

    const int srow = lane >> 3;
    const int scol = ((lane & 7) ^ srow) * 8;
    const int sw = ln & 7;
    const int half = w & 1;

    for (int js = 0; js < 8; ++js) {
        const int j0 = (ck << 9) + (js << 6);
        if (w < 2) {
            const u16* src = Qbase + (size_t)(j0 + half * 32) * 64;
#pragma unroll
            for (int c = 0; c < 4; ++c) {
                const int r = half * 32 + c * 8;
                gload_lds16(src + (size_t)(c * 8 + srow) * 64 + scol, &ldsQ[r * 64]);
            }
        } else {
            const u16* src = Vbase + (size_t)(half * 32) * 1024 + j0;
#pragma unroll
            for (int c = 0; c < 4; ++c) {
                const int r = half * 32 + c * 8;
                gload_lds16(src + (size_t)(c * 8 + srow) * 1024 + scol, &ldsV[r * 64]);
            }
        }
        __syncthreads();
#pragma unroll
        for (int it = 0; it < 2; ++it) {
#pragma unroll
            for (int jt = 0; jt < 4; ++jt) {
                const int jr = (jt << 4) + ln;
                const float pj = pn[j0 + jr];
                bf16x8 b0 = *(const bf16x8*)&ldsQ[jr * 64 + ((q ^ sw) << 3)];
                bf16x8 b1 = *(const bf16x8*)&ldsQ[jr * 64 + (((q + 4) ^ sw) << 3)];
                f32x4 c = vzero;
                c = mfma16(af[it][0], b0, c);
                c = mfma16(af[it][1], b1, c);
#pragma unroll
                for (int r = 0; r < 4; ++r) {
                    const float pe = exp2f(c[r] + fminf(pi[it][r], pj));
                    lsum[it][r] += pe;
                    Pw[((q << 2) + r) * PSTR + (jt << 4) + ln] = f2bf(pe);
                }
            }
            const bf16x8 pa0 = *(const bf16x8*)(Pw + ln * PSTR + q * 8);
            const bf16x8 pa1 = *(const bf16x8*)(Pw + ln * PSTR + 32 + q * 8);
#pragma unroll
            for (int ds = 0; ds < 4; ++ds) {
                const int vr = (ds << 4) + ln;
                bf16x8 v0 = *(const bf16x8*)&ldsV[vr * 64 + ((q ^ sw) << 3)];
                bf16x8 v1 = *(const bf16x8*)&ldsV[vr * 64 + (((q + 4) ^ sw) << 3)];
                acc[it][ds] = mfma16(pa0, v0, acc[it][ds]);
                acc[it][ds] = mfma16(pa1, v1, acc[it][ds]);
            }
        }
        __syncthreads();
    }
    u16* Oc = Ounc + ((size_t)ck << 21);
#pragma unroll
    for (int it = 0; it < 2; ++it) {
        const int t = (bh << 10) + i0 + (it << 6) + (w << 4) + (q << 2);
#pragma unroll
        for (int ds = 0; ds < 4; ++ds)
#pragma unroll
            for (int r = 0; r < 4; ++r) Oc[(size_t)(t + r) * 64 + (ds << 4) + ln] = f2bf(acc[it][ds][r]);
    }
    float s = (lsum[0][0] + lsum[0][1]) + (lsum[0][2] + lsum[0][3]) +
              (lsum[1][0] + lsum[1][1]) + (lsum[1][2] + lsum[1][3]);
#pragma unroll
    for (int o = 1; o < 64; o <<= 1) s += __shfl_xor(s, o);
    if (lane == 0) zred[w] = s;
    __syncthreads();
    if (tid == 0) blkZ[(ck << 8) + blk] = (zred[0] + zred[1]) + (zred[2] + zred[3]);
}

// out = LN(base + delta); writes fp32 and bf16. One wave per row of 512.
__global__ __launch_bounds__(256) void ln_kernel(
    const float* __restrict__ base, const float* __restrict__ delta,
    const float* __restrict__ g, const float* __restrict__ bb,
    float* __restrict__ of32, u16* __restrict__ obf) {
    const int t = blockIdx.x * 4 + (threadIdx.x >> 6);
    const int lane = threadIdx.x & 63;
    const int off = t * 512 + lane * 8;
    f32x4 a0 = *(const f32x4*)(base + off);
    f32x4 a1 = *(const f32x4*)(base + off + 4);
    f32x4 e0 = *(const f32x4*)(delta + off);
    f32x4 e1 = *(const f32x4*)(delta + off + 4);
    float v[8];
#pragma unroll
    for (int k = 0; k < 4; ++k) { v[k] = a0[k] + e0[k]; v[k + 4] = a1[k] + e1[k]; }
    float s = 0.f;
#pragma unroll
    for (int k = 0; k < 8; ++k) s += v[k];
#pragma unroll
    for (int o = 32; o > 0; o >>= 1) s += __shfl_xor(s, o);
    const float mean = s * (1.f / 512.f);
    float vs = 0.f;
#pragma unroll
    for (int k = 0; k < 8; ++k) { const float d = v[k] - mean; vs += d * d; }
#pragma unroll
    for (int o = 32; o > 0; o >>= 1) vs += __shfl_xor(vs, o);
    const float r = rsqrtf(vs * (1.f / 512.f) + 1e-9f);
    f32x4 y0, y1;
    u16x4 o0, o1;
#pragma unroll
    for (int k = 0; k < 4; ++k) {
        const int c = lane * 8 + k;
        const float ya = (v[k] - mean) * r * g[c] + bb[c];
        y0[k] = ya; o0[k] = f2bf(ya);
        const int c2 = c + 4;
        const float yb = (v[k + 4] - mean) * r * g[c2] + bb[c2];
        y1[k] = yb; o1[k] = f2bf(yb);
    }
    *(f32x4*)(of32 + off) = y0;
    *(f32x4*)(of32 + off + 4) = y1;
    *(u16x4*)(obf + off) = o0;
    *(u16x4*)(obf + off + 4) = o1;
}

// ---------------- host ----------------

extern "C" void kernel_launch(void* const* d_in, const int* in_sizes, int n_in,
                              void* d_out, int out_size, void* d_ws, size_t ws_size,
                              hipStream_t stream) {
    const float* x = (const float*)d_in[0];
    const float* mask = (const float*)d_in[1];
    const int* protok = (const int*)d_in[2];
    const float* wq = (const float*)d_in[3]; const float* bq = (const float*)d_in[4];
    const float* wk = (const float*)d_in[5]; const float* bk = (const float*)d_in[6];
    const float* wv = (const float*)d_in[7]; const float* bv = (const float*)d_in[8];
    const float* wo = (const float*)d_in[9]; const float* bo = (const float*)d_in[10];
    const float* w1 = (const float*)d_in[11]; const float* b1 = (const float*)d_in[12];
    const float* w2 = (const float*)d_in[13]; const float* b2 = (const float*)d_in[14];
    const float* ln1g = (const float*)d_in[15]; const float* ln1b = (const float*)d_in[16];
    const float* ln2g = (const float*)d_in[17]; const float* ln2b = (const float*)d_in[18];

    char* p = (char*)d_ws;
    auto take = [&](size_t bytes) -> char* {
        char* r = p;
        p += (bytes + 255) & ~(size_t)255;
        return r;
    };
    u16* wqT = (u16*)take(512 * 512 * 2);
    u16* wkT = (u16*)take(512 * 512 * 2);
    u16* wvT = (u16*)take(512 * 512 * 2);
    u16* woT = (u16*)take(512 * 512 * 2);
    u16* w1T = (u16*)take(2048 * 512 * 2);
    u16* w2T = (u16*)take(512 * 2048 * 2);
    u16* hbf = (u16*)take(4096 * 512 * 2);
    float* hf32 = (float*)take(4096 * 512 * 4);
    u16* qb = (u16*)take(32 * 1024 * 64 * 2);
    u16* kb = (u16*)take(32 * 1024 * 64 * 2);
    u16* vT = (u16*)take(32 * 64 * 1024 * 2);
    u16* Ounc = (u16*)take(2ull * 32 * 1024 * 64 * 2);  // 2 chunks, bf16
    float* blkZ = (float*)take(512 * 4);
    float* nzf = (float*)take(256);
    float* padneg = (float*)take(4096 * 4);
    float* attn = (float*)take(4096 * 512 * 4);  // aliased with ffn (disjoint lifetimes)
    float* out1f = (float*)take(4096 * 512 * 4);
    u16* out1bf = (u16*)take(4096 * 512 * 2);
    u16* f1 = (u16*)take(4096 * 2048 * 2);
    float* ffn = attn;

    // fused prep: weight transposes, x->bf16, padneg, nz count
    prep_kernel<<<dim3(4098), 256, 0, stream>>>(
        x, wq, wk, wv, wo, w1, w2, mask, protok,
        hbf, wqT, wkT, wvT, woT, w1T, w2T, padneg, nzf);

    const float* hin = x;
    for (int l = 0; l < 2; ++l) {
        // fused QKV projection: q -> [B,H,S,D]; k scaled LOG2E/8; v -> vT [B,H,D,S]
        gemm_bf16<128, 64, 0><<<dim3(24, 32), 256, 0, stream>>>(
            hbf, wqT, wkT, wvT, bq, bk, bv, qb, kb, vT, 512, 1536);
        // flash (Q/K swapped => computes A^T V), 2 i-tiles/block, 2 j-chunks
        flash_kernel<<<dim3(256, 2), 256, 0, stream>>>(kb, qb, vT, padneg, Ounc, blkZ);
        // output projection with fused scale_o (A synthesized from Ounc chunks + Z)
        gemm_wo<<<dim3(8, 64), 256, 0, stream>>>(Ounc, blkZ, nzf, woT, bo, attn);
        // out1 = LN(h + attn)
        ln_kernel<<<dim3(1024), 256, 0, stream>>>(hin, attn, ln1g, ln1b, out1f, out1bf);
        // FFN1 (bias+relu, bf16 out), 128x64 tiles (1024 blocks = 3 blocks/CU at 48 KB LDS;
        // at K=512 block-level latency dominates over MFMA density -> more blocks win)
        gemm_bf16<128, 64, 2><<<dim3(32, 32), 256, 0, stream>>>(
            out1bf, w1T, w1T, w1T, b1, b1, b1, f1, f1, f1, 512, 2048);
        // FFN2: deep-K 64x64 tiles (fp32 out + bias)
        gemm_bf16<64, 64, 1><<<dim3(8, 64), 256, 0, stream>>>(
            f1, w2T, w2T, w2T, b2, b2, b2, ffn, ffn, ffn, 2048, 512);
        // h' = LN(out1 + ffn); final layer writes d_out
        float* hout = (l == 1) ? (float*)d_out : hf32;
        ln_kernel<<<dim3(1024), 256, 0, stream>>>(out1f, ffn, ln2g, ln2b, hout, hbf);
        hin = hf32;
    }
}

// Round 13
// 318.484 us; speedup vs baseline: 1.0682x; 1.0682x over previous
//
#include <hip/hip_runtime.h>

typedef unsigned short u16;
typedef __bf16 bf16x8 __attribute__((ext_vector_type(8)));
typedef float f32x4 __attribute__((ext_vector_type(4)));
typedef unsigned int u32x4 __attribute__((ext_vector_type(4)));
typedef u16 u16x4 __attribute__((ext_vector_type(4)));

#define LOG2E 1.44269504089f
#define SOFF 16.0f  // constant softmax offset (normalization is global, any constant works)

__device__ __forceinline__ f32x4 mfma16(bf16x8 a, bf16x8 b, f32x4 c) {
    return __builtin_amdgcn_mfma_f32_16x16x32_bf16(a, b, c, 0, 0, 0);
}
__device__ __forceinline__ u16 f2bf(float f) {  // RNE fp32 -> bf16
    union { float f; unsigned u; } x; x.f = f;
    unsigned r = x.u + 0x7FFFu + ((x.u >> 16) & 1u);
    return (u16)(r >> 16);
}
__device__ __forceinline__ float bf2f(u16 u) {
    union { unsigned u; float f; } x; x.u = ((unsigned)u) << 16;
    return x.f;
}
// async global->LDS, 16B per lane, wave-uniform LDS base + lane*16
__device__ __forceinline__ void gload_lds16(const u16* g, u16* l) {
    __builtin_amdgcn_global_load_lds((const __attribute__((address_space(1))) unsigned int*)g,
                                     (__attribute__((address_space(3))) unsigned int*)l, 16, 0, 0);
}

// ---------------- fused prep kernel ----------------
__device__ __forceinline__ void transp_tile(const float* __restrict__ in, u16* __restrict__ out,
                                            int R, int C, int r0, int c0,
                                            float (*t)[33], int tid) {
    const int tx = tid & 31, ty = tid >> 5;
#pragma unroll
    for (int k = 0; k < 4; ++k) t[ty + k * 8][tx] = in[(size_t)(r0 + ty + k * 8) * C + c0 + tx];
    __syncthreads();
#pragma unroll
    for (int k = 0; k < 4; ++k) out[(size_t)(c0 + ty + k * 8) * R + r0 + tx] = f2bf(t[tx][ty + k * 8]);
}

__global__ __launch_bounds__(256) void prep_kernel(
    const float* __restrict__ x,
    const float* __restrict__ wq, const float* __restrict__ wk,
    const float* __restrict__ wv, const float* __restrict__ wo,
    const float* __restrict__ w1, const float* __restrict__ w2,
    const float* __restrict__ mask, const int* __restrict__ protok,
    u16* __restrict__ hbf, u16* __restrict__ wqT, u16* __restrict__ wkT,
    u16* __restrict__ wvT, u16* __restrict__ woT, u16* __restrict__ w1T, u16* __restrict__ w2T,
    float* __restrict__ padneg, float* __restrict__ nzf) {
    __shared__ float t[32][33];
    __shared__ int red[256];
    const int id = blockIdx.x, tid = threadIdx.x;
    if (id < 1024) {
        const int z = id >> 8, rem = id & 255;
        const float* in = z == 0 ? wq : (z == 1 ? wk : (z == 2 ? wv : wo));
        u16* out = z == 0 ? wqT : (z == 1 ? wkT : (z == 2 ? wvT : woT));
        transp_tile(in, out, 512, 512, (rem >> 4) * 32, (rem & 15) * 32, t, tid);
    } else if (id < 2048) {
        const int rem = id - 1024;  // w1 [512,2048] -> w1T [2048,512]
        transp_tile(w1, w1T, 512, 2048, (rem >> 6) * 32, (rem & 63) * 32, t, tid);
    } else if (id < 3072) {
        const int rem = id - 2048;  // w2 [2048,512] -> w2T [512,2048]
        transp_tile(w2, w2T, 2048, 512, (rem >> 4) * 32, (rem & 15) * 32, t, tid);
    } else if (id < 4096) {
        const int i = ((id - 3072) * 256 + tid) * 8;
        f32x4 a = *(const f32x4*)(x + i);
        f32x4 b = *(const f32x4*)(x + i + 4);
        u16x4 o0, o1;
#pragma unroll
        for (int k = 0; k < 4; ++k) { o0[k] = f2bf(a[k]); o1[k] = f2bf(b[k]); }
        *(u16x4*)(hbf + i) = o0;
        *(u16x4*)(hbf + i + 4) = o1;
    } else if (id == 4096) {
        for (int i = tid; i < 4096; i += 256) {
            const int b = i >> 10, s = i & 1023;
            const float m = mask[(size_t)((b << 10) + s) * 1024 + s];
            padneg[i] = (m > 0.5f) ? -1.5e9f : -SOFF;
        }
    } else {
        int c = 0;
        for (int i = tid; i < 1024; i += 256) c += (protok[i] != 0) ? 1 : 0;
        red[tid] = c;
        __syncthreads();
        for (int s = 128; s > 0; s >>= 1) {
            if (tid < s) red[tid] += red[tid + s];
            __syncthreads();
        }
        if (tid == 0) nzf[0] = (float)red[0];
    }
}

// ---------------- GEMM: C[M,N] = A[M,K](bf16) * Bt[N,K]^T(bf16) ----------------
// BK=128 as two independently-swizzled 64-wide LDS halves: one barrier pair per 128 K.
// (r11 lesson: explicit dbuf does NOT help — vmcnt is a single in-order counter.)
// (r12 lesson: FFN1 at 128x64 regresses — fewer/denser blocks win when grid >= 2/CU.)
// XCD-aware block swizzle (same-m -> same XCD). Requires gridDim.y % 8 == 0, K % 128 == 0.
// MODE 0: fused QKV -> q:[B,H,S,D] bf16, k scaled LOG2E/8, v -> vT:[B,H,D,S] bf16 (N=1536);
//         sel==2 (V) blocks write the transposed tile via LDS (contiguous 16B stores along s
//         instead of a 64-lane 2KB-stride scatter).
// MODE 1: fp32 out + bias
// MODE 2: bf16 out + bias + relu
template <int BM, int BN, int MODE>
__global__ __launch_bounds__(256) void gemm_bf16(
    const u16* __restrict__ A,
    const u16* __restrict__ Bt0, const u16* __restrict__ Bt1, const u16* __restrict__ Bt2,
    const float* __restrict__ bias0, const float* __restrict__ bias1, const float* __restrict__ bias2,
    void* __restrict__ dst0, void* __restrict__ dst1, void* __restrict__ dst2,
    const int K, const int N) {
    constexpr int BK = 128;
    constexpr int WM = BM / 2, WN = BN / 2, MI = WM / 16, NI = WN / 16;
    __shared__ u16 lA[2 * BM * 64];   // [half][row][64]
    __shared__ u16 lB[2 * BN * 64];
    const int tid = threadIdx.x;
    const int w = tid >> 6, lane = tid & 63, q = lane >> 4, ln = lane & 15;
    const int wm = w >> 1, wn = w & 1;
    const int id = blockIdx.y * gridDim.x + blockIdx.x;
    const int mper = gridDim.y >> 3;
    const int rest = id >> 3;
    const int by = (id & 7) * mper + (rest % mper);
    const int bx = rest / mper;
    const int n0 = bx * BN, m0 = by * BM;
    const int rr = lane >> 3;                 // row within an 8-row staging group
    const int cs = ((lane & 7) ^ rr) * 8;     // swizzled k-offset within a half

    const u16* Bt;
    const float* bias;
    int nb, sel = 0;
    if (MODE == 0) {
        sel = n0 >> 9;
        Bt = sel == 0 ? Bt0 : (sel == 1 ? Bt1 : Bt2);
        bias = sel == 0 ? bias0 : (sel == 1 ? bias1 : bias2);
        nb = n0 & 511;
    } else {
        Bt = Bt0; bias = bias0; nb = n0;
    }

    const f32x4 vzero = {0.f, 0.f, 0.f, 0.f};
    f32x4 acc[MI][NI];
#pragma unroll
    for (int i = 0; i < MI; ++i)
#pragma unroll
        for (int j = 0; j < NI; ++j) acc[i][j] = vzero;

    const int swa = ln & 7;  // fragment-read swizzle key (row&7 == ln&7)
    for (int k0 = 0; k0 < K; k0 += BK) {
        const u16* Ag = A + (size_t)m0 * K + k0;
        const u16* Bg = Bt + (size_t)nb * K + k0;
#pragma unroll
        for (int hh = 0; hh < 2; ++hh) {
#pragma unroll
            for (int c = 0; c < BM / 32; ++c) {
                const int r = (w * (BM / 32) + c) * 8;
                gload_lds16(Ag + (size_t)(r + rr) * K + hh * 64 + cs, &lA[hh * BM * 64 + r * 64]);
            }
#pragma unroll
            for (int c = 0; c < BN / 32; ++c) {
                const int r = (w * (BN / 32) + c) * 8;
                gload_lds16(Bg + (size_t)(r + rr) * K + hh * 64 + cs, &lB[hh * BN * 64 + r * 64]);
            }
        }
        __syncthreads();
#pragma unroll
        for (int kb = 0; kb < 4; ++kb) {
            const u16* pA = &lA[(kb >> 1) * BM * 64];
            const u16* pB = &lB[(kb >> 1) * BN * 64];
            const int kk = kb & 1;
            bf16x8 af[MI], bfr[NI];
#pragma unroll
            for (int mi = 0; mi < MI; ++mi)
                af[mi] = *(const bf16x8*)&pA[(wm * WM + mi * 16 + ln) * 64 + ((((kk << 2) + q) ^ swa) << 3)];
#pragma unroll
            for (int ni = 0; ni < NI; ++ni)
                bfr[ni] = *(const bf16x8*)&pB[(wn * WN + ni * 16 + ln) * 64 + ((((kk << 2) + q) ^ swa) << 3)];
#pragma unroll
            for (int mi = 0; mi < MI; ++mi)
#pragma unroll
                for (int ni = 0; ni < NI; ++ni) acc[mi][ni] = mfma16(af[mi], bfr[ni], acc[mi][ni]);
        }
        __syncthreads();
    }

    if (MODE == 0 && sel == 2) {
        // V blocks: one (batch bb, head hh) 128s x 64d tile. Transpose via LDS, store
        // contiguous along s: vT[((bb*8+hh)*64 + d)*1024 + ss0 + s].
        const int bb = m0 >> 10, ss0 = m0 & 1023, hh = nb >> 6;
        u16* tv = lA;  // reuse staging LDS as [64 d][136]
#pragma unroll
        for (int mi = 0; mi < MI; ++mi) {
#pragma unroll
            for (int ni = 0; ni < NI; ++ni) {
                const int d = wn * WN + ni * 16 + ln;
                const float bv = bias[nb + d];
#pragma unroll
                for (int r = 0; r < 4; ++r) {
                    const int s = wm * WM + mi * 16 + q * 4 + r;
                    tv[d * 136 + s] = f2bf(acc[mi][ni][r] + bv);
                }
            }
        }
        __syncthreads();
        const int d = tid >> 2, s0 = (tid & 3) << 5;  // 32 s-elements per thread
        u16* gdst = (u16*)dst2 + ((size_t)(((bb << 3) + hh) << 6) + d) * 1024 + ss0 + s0;
        const u16* src = tv + d * 136 + s0;
#pragma unroll
        for (int c = 0; c < 4; ++c)
            *(u32x4*)(gdst + c * 8) = *(const u32x4*)(src + c * 8);
        return;
    }

    const float scl = (MODE == 0 && sel == 1) ? 0.125f * LOG2E : 1.0f;
#pragma unroll
    for (int mi = 0; mi < MI; ++mi) {
#pragma unroll
        for (int ni = 0; ni < NI; ++ni) {
            const int col = n0 + wn * WN + ni * 16 + ln;
            const float bv = bias[MODE == 0 ? (col & 511) : col];
#pragma unroll
            for (int r = 0; r < 4; ++r) {
                const int row = m0 + wm * WM + mi * 16 + q * 4 + r;
                const float v = (acc[mi][ni][r] + bv) * scl;
                if (MODE == 0) {
                    const int cc = col & 511, hh = cc >> 6, dd = cc & 63;
                    const int bb = row >> 10, ss = row & 1023;
                    u16* dq = (u16*)(sel == 0 ? dst0 : dst1);
                    dq[(((bb << 3) + hh) * 1024 + ss) * 64 + dd] = f2bf(v);
                } else if (MODE == 1) {
                    ((float*)dst0)[(size_t)row * N + col] = v;
                } else {
                    ((u16*)dst0)[(size_t)row * N + col] = f2bf(fmaxf(v, 0.f));
                }
            }
        }
    }
}

// ---------------- WO GEMM with fused scale_o ----------------
// A[row, k=h*64+d] = (sum_c Ounc[c][bh][i][d]) * nz/Z[bh] synthesized in the staging phase.
// BK=128 (2 heads per K-tile). B (woT) keeps the DMA staging path. 64x64 tiles.
__global__ __launch_bounds__(256) void gemm_wo(
    const u16* __restrict__ Ounc, const float* __restrict__ blkZ, const float* __restrict__ nzf,
    const u16* __restrict__ Bt, const float* __restrict__ bias,
    float* __restrict__ dst) {
    constexpr int BM = 64, BN = 64, N = 512;
    constexpr int WM = 32, WN = 32, MI = 2, NI = 2;
    __shared__ u16 lA[2 * BM * 64];
    __shared__ u16 lB[2 * BN * 64];
    __shared__ float facsh[8];
    const int tid = threadIdx.x;
    const int w = tid >> 6, lane = tid & 63, q = lane >> 4, ln = lane & 15;
    const int wm = w >> 1, wn = w & 1;
    const int id = blockIdx.y * gridDim.x + blockIdx.x;  // grid 8 x 64
    const int mper = gridDim.y >> 3;
    const int rest = id >> 3;
    const int by = (id & 7) * mper + (rest % mper);
    const int bx = rest / mper;
    const int n0 = bx * BN, m0 = by * BM;
    const int b = m0 >> 10, mi0 = m0 & 1023;
    const int rr = lane >> 3;
    const int cs = ((lane & 7) ^ rr) * 8;

    // per-block: fac[h] = nz / Z[b,h], reduced from 16 blkZ partials (2 ck x 8 ig)
    {
        const int h = tid >> 5, sub = tid & 31;           // 8 h-groups of 32 threads
        float v = (sub < 16) ? blkZ[((sub >> 3) << 8) + ((b << 3) + h) * 8 + (sub & 7)] : 0.f;
#pragma unroll
        for (int o = 1; o < 32; o <<= 1) v += __shfl_xor(v, o);
        if (sub == 0) facsh[h] = nzf[0] / v;
    }
    __syncthreads();

    const f32x4 vzero = {0.f, 0.f, 0.f, 0.f};
    f32x4 acc[MI][NI];
#pragma unroll
    for (int i = 0; i < MI; ++i)
#pragma unroll
        for (int j = 0; j < NI; ++j) acc[i][j] = vzero;

    const int ra = tid >> 2;                 // A-synthesis: row (0..63)
    const int dseg = (tid & 3) * 16;         // 16 d per thread per head
    const int swa = ln & 7;
    for (int k0 = 0; k0 < 512; k0 += 128) {
        const int h0 = k0 >> 6;  // first head of this K-tile
        // ---- A synthesis: per half (head), sum 2 bf16 chunks, scale, swizzled ds_write ----
#pragma unroll
        for (int hh = 0; hh < 2; ++hh) {
            const int h = h0 + hh;
            const float fac = facsh[h];
            const size_t gi = (size_t)(((b << 3) + h) << 10) + mi0 + ra;
            float vals[16];
#pragma unroll
            for (int k = 0; k < 16; ++k) vals[k] = 0.f;
#pragma unroll
            for (int c = 0; c < 2; ++c) {
                const u16* src = Ounc + (((size_t)c) << 21) + gi * 64 + dseg;
                bf16x8 x0 = *(const bf16x8*)src;
                bf16x8 x1 = *(const bf16x8*)(src + 8);
#pragma unroll
                for (int k = 0; k < 8; ++k) { vals[k] += (float)x0[k]; vals[k + 8] += (float)x1[k]; }
            }
            u16 tmp[16];
#pragma unroll
            for (int k = 0; k < 16; ++k) tmp[k] = f2bf(vals[k] * fac);
            const int c0 = (tid & 3) * 2;
            u16* dstl = &lA[hh * BM * 64 + ra * 64];
            *(u32x4*)&dstl[(c0 ^ (ra & 7)) << 3] = *(u32x4*)&tmp[0];
            *(u32x4*)&dstl[((c0 + 1) ^ (ra & 7)) << 3] = *(u32x4*)&tmp[8];
        }
        // ---- B staging via DMA (two halves) ----
        const u16* Bg = Bt + (size_t)n0 * 512 + k0;
#pragma unroll
        for (int hh = 0; hh < 2; ++hh) {
#pragma unroll
            for (int c = 0; c < BN / 32; ++c) {
                const int r = (w * (BN / 32) + c) * 8;
                gload_lds16(Bg + (size_t)(r + rr) * 512 + hh * 64 + cs, &lB[hh * BN * 64 + r * 64]);
            }
        }
        __syncthreads();
#pragma unroll
        for (int kb = 0; kb < 4; ++kb) {
            const u16* pA = &lA[(kb >> 1) * BM * 64];
            const u16* pB = &lB[(kb >> 1) * BN * 64];
            const int kk = kb & 1;
            bf16x8 af[MI], bfr[NI];
#pragma unroll
            for (int mi = 0; mi < MI; ++mi)
                af[mi] = *(const bf16x8*)&pA[(wm * WM + mi * 16 + ln) * 64 + ((((kk << 2) + q) ^ swa) << 3)];
#pragma unroll
            for (int ni = 0; ni < NI; ++ni)
                bfr[ni] = *(const bf16x8*)&pB[(wn * WN + ni * 16 + ln) * 64 + ((((kk << 2) + q) ^ swa) << 3)];
#pragma unroll
            for (int mi = 0; mi < MI; ++mi)
#pragma unroll
                for (int ni = 0; ni < NI; ++ni) acc[mi][ni] = mfma16(af[mi], bfr[ni], acc[mi][ni]);
        }
        __syncthreads();
    }

#pragma unroll
    for (int mi = 0; mi < MI; ++mi) {
#pragma unroll
        for (int ni = 0; ni < NI; ++ni) {
            const int col = n0 + wn * WN + ni * 16 + ln;
            const float bv = bias[col];
#pragma unroll
            for (int r = 0; r < 4; ++r) {
                const int row = m0 + wm * WM + mi * 16 + q * 4 + r;
                dst[(size_t)row * N + col] = acc[mi][ni][r] + bv;
            }
        }
    }
}

// ---------------- flash attention: 2 i-tiles/block, 2 j-chunks, LDS-staged tiles ----------------
#define PSTR 68
__global__ __launch_bounds__(256) void flash_kernel(
    const u16* __restrict__ Kb, const u16* __restrict__ Qb, const u16* __restrict__ VT,
    const float* __restrict__ padneg,
    u16* __restrict__ Ounc, float* __restrict__ blkZ) {
    __shared__ u16 ldsQ[64 * 64];   // [j-local][d], row 128B, swizzled chunks
    __shared__ u16 ldsV[64 * 64];   // [d][j-local], row 128B, swizzled chunks
    __shared__ u16 P[4][16 * PSTR];
    __shared__ float zred[4];
    const int blk = blockIdx.x, ck = blockIdx.y;  // blk = bh*8+ig, ck in {0,1}
    const int ig = blk & 7, bh = blk >> 3, b = bh >> 3;
    const int i0 = ig << 7;
    const int tid = threadIdx.x;
    const int w = tid >> 6, lane = tid & 63, q = lane >> 4, ln = lane & 15;

    bf16x8 af[2][2];
    float pi[2][4];
    const float* pn = padneg + (b << 10);
#pragma unroll
    for (int it = 0; it < 2; ++it) {
        const u16* Ka = Kb + ((bh << 10) + i0 + (it << 6) + (w << 4) + ln) * 64;
        af[it][0] = *(const bf16x8*)(Ka + q * 8);
        af[it][1] = *(const bf16x8*)(Ka + 32 + q * 8);
#pragma unroll
        for (int r = 0; r < 4; ++r) pi[it][r] = pn[i0 + (it << 6) + (w << 4) + (q << 2) + r];
    }
    const u16* Qbase = Qb + (bh << 10) * 64;
    const u16* Vbase = VT + (bh << 6) * 1024;

    float lsum[2][4] = {{0.f, 0.f, 0.f, 0.f}, {0.f, 0.f, 0.f, 0.f}};
    const f32x4 vzero = {0.f, 0.f, 0.f, 0.f};
    f32x4 acc[2][4];
#pragma unroll
    for (int it = 0; it < 2; ++it)
#pragma unroll
        for (int ds = 0; ds < 4; ++ds) acc[it][ds] = vzero;
    u16* Pw = &P[w][0];

    const int srow = lane >> 3;
    const int scol = ((lane & 7) ^ srow) * 8;
    const int sw = ln & 7;
    const int half = w & 1;

    for (int js = 0; js < 8; ++js) {
        const int j0 = (ck << 9) + (js << 6);
        if (w < 2) {
            const u16* src = Qbase + (size_t)(j0 + half * 32) * 64;
#pragma unroll
            for (int c = 0; c < 4; ++c) {
                const int r = half * 32 + c * 8;
                gload_lds16(src + (size_t)(c * 8 + srow) * 64 + scol, &ldsQ[r * 64]);
            }
        } else {
            const u16* src = Vbase + (size_t)(half * 32) * 1024 + j0;
#pragma unroll
            for (int c = 0; c < 4; ++c) {
                const int r = half * 32 + c * 8;
                gload_lds16(src + (size_t)(c * 8 + srow) * 1024 + scol, &ldsV[r * 64]);
            }
        }
        __syncthreads();
#pragma unroll
        for (int it = 0; it < 2; ++it) {
#pragma unroll
            for (int jt = 0; jt < 4; ++jt) {
                const int jr = (jt << 4) + ln;
                const float pj = pn[j0 + jr];
                bf16x8 b0 = *(const bf16x8*)&ldsQ[jr * 64 + ((q ^ sw) << 3)];
                bf16x8 b1 = *(const bf16x8*)&ldsQ[jr * 64 + (((q + 4) ^ sw) << 3)];
                f32x4 c = vzero;
                c = mfma16(af[it][0], b0, c);
                c = mfma16(af[it][1], b1, c);
#pragma unroll
                for (int r = 0; r < 4; ++r) {
                    const float pe = exp2f(c[r] + fminf(pi[it][r], pj));
                    lsum[it][r] += pe;
                    Pw[((q << 2) + r) * PSTR + (jt << 4) + ln] = f2bf(pe);
                }
            }
            const bf16x8 pa0 = *(const bf16x8*)(Pw + ln * PSTR + q * 8);
            const bf16x8 pa1 = *(const bf16x8*)(Pw + ln * PSTR + 32 + q * 8);
#pragma unroll
            for (int ds = 0; ds < 4; ++ds) {
                const int vr = (ds << 4) + ln;
                bf16x8 v0 = *(const bf16x8*)&ldsV[vr * 64 + ((q ^ sw) << 3)];
                bf16x8 v1 = *(const bf16x8*)&ldsV[vr * 64 + (((q + 4) ^ sw) << 3)];
                acc[it][ds] = mfma16(pa0, v0, acc[it][ds]);
                acc[it][ds] = mfma16(pa1, v1, acc[it][ds]);
            }
        }
        __syncthreads();
    }
    u16* Oc = Ounc + ((size_t)ck << 21);
#pragma unroll
    for (int it = 0; it < 2; ++it) {
        const int t = (bh << 10) + i0 + (it << 6) + (w << 4) + (q << 2);
#pragma unroll
        for (int ds = 0; ds < 4; ++ds)
#pragma unroll
            for (int r = 0; r < 4; ++r) Oc[(size_t)(t + r) * 64 + (ds << 4) + ln] = f2bf(acc[it][ds][r]);
    }
    float s = (lsum[0][0] + lsum[0][1]) + (lsum[0][2] + lsum[0][3]) +
              (lsum[1][0] + lsum[1][1]) + (lsum[1][2] + lsum[1][3]);
#pragma unroll
    for (int o = 1; o < 64; o <<= 1) s += __shfl_xor(s, o);
    if (lane == 0) zred[w] = s;
    __syncthreads();
    if (tid == 0) blkZ[(ck << 8) + blk] = (zred[0] + zred[1]) + (zred[2] + zred[3]);
}

// out = LN(base + delta); writes fp32 and bf16. One wave per row of 512.
__global__ __launch_bounds__(256) void ln_kernel(
    const float* __restrict__ base, const float* __restrict__ delta,
    const float* __restrict__ g, const float* __restrict__ bb,
    float* __restrict__ of32, u16* __restrict__ obf) {
    const int t = blockIdx.x * 4 + (threadIdx.x >> 6);
    const int lane = threadIdx.x & 63;
    const int off = t * 512 + lane * 8;
    f32x4 a0 = *(const f32x4*)(base + off);
    f32x4 a1 = *(const f32x4*)(base + off + 4);
    f32x4 e0 = *(const f32x4*)(delta + off);
    f32x4 e1 = *(const f32x4*)(delta + off + 4);
    float v[8];
#pragma unroll
    for (int k = 0; k < 4; ++k) { v[k] = a0[k] + e0[k]; v[k + 4] = a1[k] + e1[k]; }
    float s = 0.f;
#pragma unroll
    for (int k = 0; k < 8; ++k) s += v[k];
#pragma unroll
    for (int o = 32; o > 0; o >>= 1) s += __shfl_xor(s, o);
    const float mean = s * (1.f / 512.f);
    float vs = 0.f;
#pragma unroll
    for (int k = 0; k < 8; ++k) { const float d = v[k] - mean; vs += d * d; }
#pragma unroll
    for (int o = 32; o > 0; o >>= 1) vs += __shfl_xor(vs, o);
    const float r = rsqrtf(vs * (1.f / 512.f) + 1e-9f);
    f32x4 y0, y1;
    u16x4 o0, o1;
#pragma unroll
    for (int k = 0; k < 4; ++k) {
        const int c = lane * 8 + k;
        const float ya = (v[k] - mean) * r * g[c] + bb[c];
        y0[k] = ya; o0[k] = f2bf(ya);
        const int c2 = c + 4;
        const float yb = (v[k + 4] - mean) * r * g[c2] + bb[c2];
        y1[k] = yb; o1[k] = f2bf(yb);
    }
    *(f32x4*)(of32 + off) = y0;
    *(f32x4*)(of32 + off + 4) = y1;
    *(u16x4*)(obf + off) = o0;
    *(u16x4*)(obf + off + 4) = o1;
}

// ---------------- host ----------------

extern "C" void kernel_launch(void* const* d_in, const int* in_sizes, int n_in,
                              void* d_out, int out_size, void* d_ws, size_t ws_size,
                              hipStream_t stream) {
    const float* x = (const float*)d_in[0];
    const float* mask = (const float*)d_in[1];
    const int* protok = (const int*)d_in[2];
    const float* wq = (const float*)d_in[3]; const float* bq = (const float*)d_in[4];
    const float* wk = (const float*)d_in[5]; const float* bk = (const float*)d_in[6];
    const float* wv = (const float*)d_in[7]; const float* bv = (const float*)d_in[8];
    const float* wo = (const float*)d_in[9]; const float* bo = (const float*)d_in[10];
    const float* w1 = (const float*)d_in[11]; const float* b1 = (const float*)d_in[12];
    const float* w2 = (const float*)d_in[13]; const float* b2 = (const float*)d_in[14];
    const float* ln1g = (const float*)d_in[15]; const float* ln1b = (const float*)d_in[16];
    const float* ln2g = (const float*)d_in[17]; const float* ln2b = (const float*)d_in[18];

    char* p = (char*)d_ws;
    auto take = [&](size_t bytes) -> char* {
        char* r = p;
        p += (bytes + 255) & ~(size_t)255;
        return r;
    };
    u16* wqT = (u16*)take(512 * 512 * 2);
    u16* wkT = (u16*)take(512 * 512 * 2);
    u16* wvT = (u16*)take(512 * 512 * 2);
    u16* woT = (u16*)take(512 * 512 * 2);
    u16* w1T = (u16*)take(2048 * 512 * 2);
    u16* w2T = (u16*)take(512 * 2048 * 2);
    u16* hbf = (u16*)take(4096 * 512 * 2);
    float* hf32 = (float*)take(4096 * 512 * 4);
    u16* qb = (u16*)take(32 * 1024 * 64 * 2);
    u16* kb = (u16*)take(32 * 1024 * 64 * 2);
    u16* vT = (u16*)take(32 * 64 * 1024 * 2);
    u16* Ounc = (u16*)take(2ull * 32 * 1024 * 64 * 2);  // 2 chunks, bf16
    float* blkZ = (float*)take(512 * 4);
    float* nzf = (float*)take(256);
    float* padneg = (float*)take(4096 * 4);
    float* attn = (float*)take(4096 * 512 * 4);  // aliased with ffn (disjoint lifetimes)
    float* out1f = (float*)take(4096 * 512 * 4);
    u16* out1bf = (u16*)take(4096 * 512 * 2);
    u16* f1 = (u16*)take(4096 * 2048 * 2);
    float* ffn = attn;

    // fused prep: weight transposes, x->bf16, padneg, nz count
    prep_kernel<<<dim3(4098), 256, 0, stream>>>(
        x, wq, wk, wv, wo, w1, w2, mask, protok,
        hbf, wqT, wkT, wvT, woT, w1T, w2T, padneg, nzf);

    const float* hin = x;
    for (int l = 0; l < 2; ++l) {
        // fused QKV projection: q -> [B,H,S,D]; k scaled LOG2E/8; v -> vT [B,H,D,S]
        gemm_bf16<128, 64, 0><<<dim3(24, 32), 256, 0, stream>>>(
            hbf, wqT, wkT, wvT, bq, bk, bv, qb, kb, vT, 512, 1536);
        // flash (Q/K swapped => computes A^T V), 2 i-tiles/block, 2 j-chunks
        flash_kernel<<<dim3(256, 2), 256, 0, stream>>>(kb, qb, vT, padneg, Ounc, blkZ);
        // output projection with fused scale_o (A synthesized from Ounc chunks + Z)
        gemm_wo<<<dim3(8, 64), 256, 0, stream>>>(Ounc, blkZ, nzf, woT, bo, attn);
        // out1 = LN(h + attn)
        ln_kernel<<<dim3(1024), 256, 0, stream>>>(hin, attn, ln1g, ln1b, out1f, out1bf);
        // FFN1 (bias+relu, bf16 out), 128x128 tiles (r12: 128x64 regressed)
        gemm_bf16<128, 128, 2><<<dim3(16, 32), 256, 0, stream>>>(
            out1bf, w1T, w1T, w1T, b1, b1, b1, f1, f1, f1, 512, 2048);
        // FFN2: deep-K 64x64 tiles (fp32 out + bias)
        gemm_bf16<64, 64, 1><<<dim3(8, 64), 256, 0, stream>>>(
            f1, w2T, w2T, w2T, b2, b2, b2, ffn, ffn, ffn, 2048, 512);
        // h' = LN(out1 + ffn); final layer writes d_out
        float* hout = (l == 1) ? (float*)d_out : hf32;
        ln_kernel<<<dim3(1024), 256, 0, stream>>>(out1f, ffn, ln2g, ln2b, hout, hbf);
        hin = hf32;
    }
}